// Round 7
// baseline (424.107 us; speedup 1.0000x reference)
//
#include <hip/hip_runtime.h>
#include <math.h>

// Problem constants
#define BB    8192
#define NN    512
#define KKN   8
#define HH    1024
#define OUTD  (NN * (2 * KKN + 1))   // 8704

typedef unsigned short ushort_t;
typedef __bf16 bf16x8 __attribute__((ext_vector_type(8)));
typedef float  f32x4  __attribute__((ext_vector_type(4)));

// float -> bf16 round-to-nearest-even
__device__ inline ushort_t f2bf(float f) {
    unsigned int u = __float_as_uint(f);
    unsigned int r = (u + 0x7fffu + ((u >> 16) & 1u)) >> 16;
    return (ushort_t)r;
}
__device__ inline float bf2f(ushort_t u) {
    return __uint_as_float(((unsigned int)u) << 16);
}

// 5-op tanh: 1 - 2/(e^{2x}+1). Saturates correctly for |x| large.
__device__ inline float fast_tanh(float x) {
    float t = __expf(x + x);
    return fmaf(-2.f, __builtin_amdgcn_rcpf(t + 1.f), 1.f);
}

// ---------------------------------------------------------------------------
// conv_v: a0b[b][n] = bf16(v_in[b][n] - 0.5), n in [0,512). v_in rows are 1024.
// ---------------------------------------------------------------------------
__global__ __launch_bounds__(256) void conv_v(
    const float* __restrict__ v_in, ushort_t* __restrict__ a0b)
{
    int t = blockIdx.x * 256 + threadIdx.x;          // 0 .. B*512/2-1
    int e0 = t * 2;
    int b = e0 >> 9;
    int n = e0 & 511;
    const float2 v = *(const float2*)(v_in + (size_t)b * (2 * NN) + n);
    ushort_t* o = a0b + (size_t)b * NN + n;
    o[0] = f2bf(v.x - 0.5f);
    o[1] = f2bf(v.y - 0.5f);
}

// ---------------------------------------------------------------------------
// transpose_cvt: W (Kd x Nd fp32 row-major) -> WT (Nd x Kd bf16 row-major)
// PERM: out-row r is remapped to (r%17)*512 + r/17 (plane-major net layout)
// ---------------------------------------------------------------------------
template <bool PERM>
__global__ __launch_bounds__(256) void transpose_cvt(
    const float* __restrict__ W, ushort_t* __restrict__ WT, int Kd, int Nd)
{
    __shared__ float tile[32][33];
    const int bx = blockIdx.x * 32;   // n base
    const int by = blockIdx.y * 32;   // k base
    const int tx = threadIdx.x;       // 0..31
    const int ty = threadIdx.y;       // 0..7
#pragma unroll
    for (int i = 0; i < 32; i += 8)
        tile[ty + i][tx] = W[(size_t)(by + ty + i) * Nd + bx + tx];
    __syncthreads();
#pragma unroll
    for (int i = 0; i < 32; i += 8) {
        int r = bx + ty + i;
        if (PERM) r = (r % 17) * 512 + (r / 17);
        WT[(size_t)r * Kd + by + tx] = f2bf(tile[tx][ty + i]);
    }
}

// ---------------------------------------------------------------------------
// bf16 MFMA GEMM (m97 structure + bank-conflict swizzle + XCD band swizzle):
//   C = bf16(tanh(A @ B + bias))
//   A : M x K bf16 row-major; BT: N x K bf16 row-major; C: M x N bf16.
// 128x128 tile, BK=32, 256 threads = 2x2 waves, 4x4 16x16x32 MFMAs per wave.
//
// XCD band swizzle: 1D grid, XCD = blockIdx % 8 (dispatch heuristic,
// perf-only). XCD j owns block-rows [j*gy/8, (j+1)*gy/8): its A band
// (8 x 256 KB = 2 MB) stays L2-resident, and all XCDs walk the same B
// column-tile concurrently (same s -> same bx) for LLC temporal locality.
//
// LDS swizzle (R5, verified 0 conflicts): row r's k-chunk g stored at
// slot-pos (g+(r>>1))&3 by permuting WHICH global chunk each lane fetches.
// ---------------------------------------------------------------------------
template <bool PERM_BIAS>
__global__ __launch_bounds__(256) void gemm_bt_tanh(
    const ushort_t* __restrict__ A,
    const ushort_t* __restrict__ BT,
    const float* __restrict__ bias,
    ushort_t* __restrict__ C,
    int N_, int K, int gx, int gy)
{
    __shared__ __align__(16) ushort_t sA[128 * 32];   // [row][k-chunk swizzled] 8 KB
    __shared__ __align__(16) ushort_t sB[128 * 32];

    const int t    = threadIdx.x;
    const int lane = t & 63;
    const int w    = t >> 6;
    const int wy   = w >> 1;
    const int wx   = w & 1;
    const int quad = lane >> 4;
    const int l16  = lane & 15;

    // XCD band decode (gy always a multiple of 8 here)
    const int id  = blockIdx.x;
    const int j   = id & 7;            // XCD (assumed id % 8)
    const int s   = id >> 3;
    const int per = gy >> 3;           // block-rows per XCD band
    const int byi = j * per + s / gx;
    const int bxi = s % gx;

    const int brow = byi * 128;
    const int bcol = bxi * 128;

    f32x4 acc[4][4] = {};

    const int cwb = (t & ~63);       // wave-uniform chunk base

    // staging: slot c = p*256 + t holds (row r = c>>2, k-chunk g = ((c&3)-(r>>1))&3)
    int rS[2], gS[2];
#pragma unroll
    for (int p = 0; p < 2; ++p) {
        const int c = p * 256 + t;
        rS[p] = c >> 2;
        gS[p] = ((c & 3) - (rS[p] >> 1)) & 3;
    }

    // fragment LDS byte-offsets (k0-invariant)
    int offA[4], offB[4];
#pragma unroll
    for (int i = 0; i < 4; ++i) {
        const int rowA = wy * 64 + i * 16 + l16;
        offA[i] = rowA * 32 + ((quad + (rowA >> 1)) & 3) * 8;
        const int rowB = wx * 64 + i * 16 + l16;
        offB[i] = rowB * 32 + ((quad + (rowB >> 1)) & 3) * 8;
    }

    for (int k0 = 0; k0 < K; k0 += 32) {
        __syncthreads();
#pragma unroll
        for (int p = 0; p < 2; ++p) {
            const int cb = p * 256 + cwb;
            const ushort_t* ga = A  + (size_t)(brow + rS[p]) * K + k0 + gS[p] * 8;
            const ushort_t* gb = BT + (size_t)(bcol + rS[p]) * K + k0 + gS[p] * 8;
            __builtin_amdgcn_global_load_lds(
                (const __attribute__((address_space(1))) void*)ga,
                (__attribute__((address_space(3))) void*)(sA + (size_t)cb * 8), 16, 0, 0);
            __builtin_amdgcn_global_load_lds(
                (const __attribute__((address_space(1))) void*)gb,
                (__attribute__((address_space(3))) void*)(sB + (size_t)cb * 8), 16, 0, 0);
        }
        __syncthreads();

        bf16x8 af[4], bfr[4];
#pragma unroll
        for (int i = 0; i < 4; ++i) {
            af[i]  = *(const bf16x8*)(sA + offA[i]);
            bfr[i] = *(const bf16x8*)(sB + offB[i]);
        }
#pragma unroll
        for (int i = 0; i < 4; ++i)
#pragma unroll
            for (int j2 = 0; j2 < 4; ++j2)
                acc[i][j2] = __builtin_amdgcn_mfma_f32_16x16x32_bf16(
                    af[i], bfr[j2], acc[i][j2], 0, 0, 0);
    }

    // epilogue: C/D mapping col=lane&15, row=quad*4+reg  [m89/m91 verified]
    const int row0 = brow + wy * 64;
    const int col0 = bcol + wx * 64;
#pragma unroll
    for (int i = 0; i < 4; ++i) {
#pragma unroll
        for (int j2 = 0; j2 < 4; ++j2) {
            const int col = col0 + j2 * 16 + l16;
            const int bidx = PERM_BIAS ? ((col & 511) * 17 + (col >> 9)) : col;
            const float bv = bias[bidx];
#pragma unroll
            for (int r = 0; r < 4; ++r) {
                const int row = row0 + i * 16 + quad * 4 + r;
                C[(size_t)row * N_ + col] = f2bf(fast_tanh(acc[i][j2][r] + bv));
            }
        }
    }
}

// ---------------------------------------------------------------------------
// Spline postprocess, plane-major net layout: net[b][p*512 + n] holds value
// p of unit n (p<9: h_net, p>=9: w_net). One block per batch row, 256
// threads; thread t handles units 2t, 2t+1 via dword plane loads (coalesced).
// ---------------------------------------------------------------------------
__global__ __launch_bounds__(256) void spline_post(
    const ushort_t* __restrict__ net,   // rows x OUTD bf16, plane-major
    const float* __restrict__ v_in,     // rows x 2N
    const float* __restrict__ ld_in,    // rows
    float* __restrict__ v_out,          // rows x 2N
    float* __restrict__ ld_out)         // rows
{
    const int b = blockIdx.x;
    const int t = threadIdx.x;          // 0..255

    // 17 coalesced dword loads: planes p, units {2t, 2t+1}
    unsigned int pl[17];
    const ushort_t* base = net + (size_t)b * OUTD + 2 * t;
#pragma unroll
    for (int p = 0; p < 17; ++p)
        pl[p] = *(const unsigned int*)(base + p * 512);

    // passive copy (units 2t, 2t+1)
    {
        const float2 vp = *(const float2*)(v_in + (size_t)b * (2 * NN) + 2 * t);
        *(float2*)(v_out + (size_t)b * (2 * NN) + 2 * t) = vp;
    }
    const float2 va2 = *(const float2*)(v_in + (size_t)b * (2 * NN) + NN + 2 * t);

    float vact[2];
    float lt_sum = 0.f;
#pragma unroll 1
    for (int u = 0; u < 2; ++u) {
        const int sh = u * 16;
        float t17[17];
#pragma unroll
        for (int p = 0; p < 17; ++p)
            t17[p] = bf2f((ushort_t)(pl[p] >> sh));

        // softmax over w_net = t17[9..16]
        float m = t17[9];
#pragma unroll
        for (int i = 10; i < 17; i++) m = fmaxf(m, t17[i]);
        float wn[8], wsum = 0.f;
#pragma unroll
        for (int i = 0; i < 8; i++) { wn[i] = __expf(t17[9 + i] - m); wsum += wn[i]; }
        const float winv = 1.f / wsum;
#pragma unroll
        for (int i = 0; i < 8; i++) wn[i] *= winv;

        float eh[9];
#pragma unroll
        for (int i = 0; i < 9; i++) eh[i] = __expf(t17[i]);
        float denom = 0.f;
#pragma unroll
        for (int k = 0; k < 8; k++) denom += 0.5f * wn[k] * (eh[k] + eh[k + 1]);
        const float dinv = 1.f / denom;
        float hn[9];
#pragma unroll
        for (int i = 0; i < 9; i++) hn[i] = eh[i] * dinv;

        float kx[9], ky[9];
        kx[0] = 0.f; ky[0] = 0.f;
#pragma unroll
        for (int k = 0; k < 8; k++) {
            kx[k + 1] = kx[k] + wn[k];
            ky[k + 1] = ky[k] + 0.5f * wn[k] * (hn[k] + hn[k + 1]);
        }

        const float va = (u == 0) ? va2.x : va2.y;
        int cnt = 0;
#pragma unroll
        for (int j = 0; j < 9; j++) cnt += (kx[j] < va) ? 1 : 0;
        int k = cnt - 1;
        k = k < 0 ? 0 : (k > KKN - 1 ? KKN - 1 : k);

        const float wseg = wn[k];
        const float hlo = hn[k], hhi = hn[k + 1];
        const float xlo = kx[k], ylo = ky[k];
        const float alpha = (va - xlo) / wseg;
        vact[u] = ylo + alpha * hlo * wseg + 0.5f * alpha * alpha * (hhi - hlo) * wseg;
        lt_sum += __logf(hlo + alpha * (hhi - hlo));
    }

    *(float2*)(v_out + (size_t)b * (2 * NN) + NN + 2 * t) = make_float2(vact[0], vact[1]);

    // reduce lt_sum across 256 threads (4 waves)
    __shared__ float wred[4];
#pragma unroll
    for (int o = 32; o > 0; o >>= 1) lt_sum += __shfl_down(lt_sum, o, 64);
    if ((t & 63) == 0) wred[t >> 6] = lt_sum;
    __syncthreads();
    if (t == 0)
        ld_out[b] = ld_in[b] - (wred[0] + wred[1] + wred[2] + wred[3]);
}

// ---------------------------------------------------------------------------
extern "C" void kernel_launch(void* const* d_in, const int* in_sizes, int n_in,
                              void* d_out, int out_size, void* d_ws, size_t ws_size,
                              hipStream_t stream)
{
    const float* v_in = (const float*)d_in[0];   // B x 2N
    const float* ld   = (const float*)d_in[1];   // B x 1
    const float* W1   = (const float*)d_in[2];   // N x H
    const float* b1   = (const float*)d_in[3];   // H
    const float* W2   = (const float*)d_in[4];   // H x H
    const float* b2   = (const float*)d_in[5];   // H
    const float* W3   = (const float*)d_in[6];   // H x OUTD
    const float* b3   = (const float*)d_in[7];   // OUTD

    float* out    = (float*)d_out;
    float* v_out  = out;                           // B*2N
    float* ld_out = out + (size_t)BB * (2 * NN);   // B

    // Workspace tiers (R3-verified: full tier 172Mi fits):
    //   [0, region)       chunk net buffer (plane-major); a0b + x1b alias here
    //   [region, +16Mi)   x2b ; then W1T (1Mi) W2T (2Mi) W3T (17Mi)
    const size_t Mi = 1048576;
    int    chunk;
    size_t region;
    if      (ws_size >= 172 * Mi) { chunk = 8192; region = 136 * Mi; }
    else if (ws_size >= 104 * Mi) { chunk = 4096; region =  68 * Mi; }
    else if (ws_size >=  70 * Mi) { chunk = 2048; region =  34 * Mi; }
    else                          { chunk = 1024; region =  24 * Mi; }

    char* ws = (char*)d_ws;
    ushort_t* a0b = (ushort_t*)(ws);
    ushort_t* x1b = (ushort_t*)(ws + 8 * Mi);
    ushort_t* netc = (ushort_t*)(ws);                       // chunk buffer
    ushort_t* x2b = (ushort_t*)(ws + region);
    ushort_t* W1T = (ushort_t*)(ws + region + 16 * Mi);
    ushort_t* W2T = (ushort_t*)(ws + region + 17 * Mi);
    ushort_t* W3T = (ushort_t*)(ws + region + 19 * Mi);

    // conversions
    conv_v<<<dim3(BB * NN / 2 / 256), dim3(256), 0, stream>>>(v_in, a0b);
    transpose_cvt<false><<<dim3(HH / 32, NN / 32),   dim3(32, 8), 0, stream>>>(W1, W1T, NN, HH);
    transpose_cvt<false><<<dim3(HH / 32, HH / 32),   dim3(32, 8), 0, stream>>>(W2, W2T, HH, HH);
    transpose_cvt<true ><<<dim3(OUTD / 32, HH / 32), dim3(32, 8), 0, stream>>>(W3, W3T, HH, OUTD);

    // GEMM1: x1 = tanh((v_passive-0.5) @ W1 + b1)   M=8192 N=1024 K=512
    {
        int gx = HH / 128, gy = BB / 128;
        gemm_bt_tanh<false><<<dim3(gx * gy), dim3(256), 0, stream>>>(
            a0b, W1T, b1, x1b, HH, NN, gx, gy);
    }
    // GEMM2: x2 = tanh(x1 @ W2 + b2)                M=8192 N=1024 K=1024
    {
        int gx = HH / 128, gy = BB / 128;
        gemm_bt_tanh<false><<<dim3(gx * gy), dim3(256), 0, stream>>>(
            x1b, W2T, b2, x2b, HH, HH, gx, gy);
    }

    // GEMM3 + spline, chunked (single pass when chunk==8192)
    for (int c = 0; c < BB / chunk; ++c) {
        const ushort_t* xa = x2b + (size_t)c * chunk * HH;
        int gx = OUTD / 128, gy = chunk / 128;
        gemm_bt_tanh<true><<<dim3(gx * gy), dim3(256), 0, stream>>>(
            xa, W3T, b3, netc, OUTD, HH, gx, gy);
        spline_post<<<dim3(chunk), dim3(256), 0, stream>>>(
            netc,
            v_in   + (size_t)c * chunk * (2 * NN),
            ld     + (size_t)c * chunk,
            v_out  + (size_t)c * chunk * (2 * NN),
            ld_out + (size_t)c * chunk);
    }
}

// Round 8
// 401.419 us; speedup vs baseline: 1.0565x; 1.0565x over previous
//
#include <hip/hip_runtime.h>
#include <math.h>

// Problem constants
#define BB    8192
#define NN    512
#define KKN   8
#define HH    1024
#define OUTD  (NN * (2 * KKN + 1))   // 8704

typedef unsigned short ushort_t;
typedef __bf16 bf16x8 __attribute__((ext_vector_type(8)));
typedef float  f32x16 __attribute__((ext_vector_type(16)));

// float -> bf16 round-to-nearest-even
__device__ inline ushort_t f2bf(float f) {
    unsigned int u = __float_as_uint(f);
    unsigned int r = (u + 0x7fffu + ((u >> 16) & 1u)) >> 16;
    return (ushort_t)r;
}
__device__ inline float bf2f(ushort_t u) {
    return __uint_as_float(((unsigned int)u) << 16);
}

// 5-op tanh: 1 - 2/(e^{2x}+1). Saturates correctly for |x| large.
__device__ inline float fast_tanh(float x) {
    float t = __expf(x + x);
    return fmaf(-2.f, __builtin_amdgcn_rcpf(t + 1.f), 1.f);
}

// ---------------------------------------------------------------------------
// conv_v: a0b[b][n] = bf16(v_in[b][n] - 0.5), n in [0,512). v_in rows are 1024.
// ---------------------------------------------------------------------------
__global__ __launch_bounds__(256) void conv_v(
    const float* __restrict__ v_in, ushort_t* __restrict__ a0b)
{
    int t = blockIdx.x * 256 + threadIdx.x;          // 0 .. B*512/2-1
    int e0 = t * 2;
    int b = e0 >> 9;
    int n = e0 & 511;
    const float2 v = *(const float2*)(v_in + (size_t)b * (2 * NN) + n);
    ushort_t* o = a0b + (size_t)b * NN + n;
    o[0] = f2bf(v.x - 0.5f);
    o[1] = f2bf(v.y - 0.5f);
}

// ---------------------------------------------------------------------------
// transpose_cvt: W (Kd x Nd fp32 row-major) -> WT (Nd x Kd bf16 row-major)
// PERM: out-row r is remapped to (r%17)*512 + r/17 (plane-major net layout)
// ---------------------------------------------------------------------------
template <bool PERM>
__global__ __launch_bounds__(256) void transpose_cvt(
    const float* __restrict__ W, ushort_t* __restrict__ WT, int Kd, int Nd)
{
    __shared__ float tile[32][33];
    const int bx = blockIdx.x * 32;   // n base
    const int by = blockIdx.y * 32;   // k base
    const int tx = threadIdx.x;       // 0..31
    const int ty = threadIdx.y;       // 0..7
#pragma unroll
    for (int i = 0; i < 32; i += 8)
        tile[ty + i][tx] = W[(size_t)(by + ty + i) * Nd + bx + tx];
    __syncthreads();
#pragma unroll
    for (int i = 0; i < 32; i += 8) {
        int r = bx + ty + i;
        if (PERM) r = (r % 17) * 512 + (r / 17);
        WT[(size_t)r * Kd + by + tx] = f2bf(tile[tx][ty + i]);
    }
}

// ---------------------------------------------------------------------------
// bf16 MFMA GEMM, 32x32x16 shape: C = bf16(tanh(A @ B + bias))
//   A : M x K bf16 row-major; BT: N x K bf16 row-major; C: M x N bf16.
// 128x128 block tile, BK=32, 256 threads = 2x2 waves; each wave owns a
// 64x64 sub-tile = 2x2 grid of 32x32 MFMA tiles, 2 k-steps of 16 per BK.
// Only 4 fragments (16 VGPRs) live per k-step -> total regs <= 128 with the
// 64 acc regs => 4 waves/SIMD occupancy target.
//
// LDS swizzle (R5, measured 0 conflicts): row r's 16B k-chunk g stored at
// slot-pos (g+(r>>1))&3, applied by permuting WHICH global chunk each lane
// fetches (global_load_lds dest is base+lane*16, not scatterable).
// ---------------------------------------------------------------------------
template <bool PERM_BIAS>
__global__ __launch_bounds__(256) void gemm_bt_tanh(
    const ushort_t* __restrict__ A,
    const ushort_t* __restrict__ BT,
    const float* __restrict__ bias,
    ushort_t* __restrict__ C,
    int N_, int K)
{
    __shared__ __align__(16) ushort_t sA[128 * 32];   // [row][k-chunk swizzled] 8 KB
    __shared__ __align__(16) ushort_t sB[128 * 32];

    const int t    = threadIdx.x;
    const int lane = t & 63;
    const int w    = t >> 6;
    const int wy   = w >> 1;
    const int wx   = w & 1;
    const int l31  = lane & 31;
    const int h    = lane >> 5;       // k-half within fragment

    const int brow = blockIdx.y * 128;
    const int bcol = blockIdx.x * 128;

    f32x16 acc[2][2] = {};

    const int cwb = (t & ~63);       // wave-uniform chunk base

    // staging: slot c = p*256 + t holds (row r = c>>2, k-chunk g = ((c&3)-(r>>1))&3)
    int rS[2], gS[2];
#pragma unroll
    for (int p = 0; p < 2; ++p) {
        const int c = p * 256 + t;
        rS[p] = c >> 2;
        gS[p] = ((c & 3) - (rS[p] >> 1)) & 3;
    }

    // fragment LDS offsets (ushort units), k0-invariant.
    // A frag (32x16): row = wy*64 + ti*32 + l31, k-chunk g = 2*ks + h
    // B frag (32x16): row = wx*64 + tj*32 + l31 (BT rows are C-cols)
    int offA[2][2], offB[2][2];
#pragma unroll
    for (int ks = 0; ks < 2; ++ks)
#pragma unroll
        for (int ti = 0; ti < 2; ++ti) {
            const int rA = wy * 64 + ti * 32 + l31;
            offA[ks][ti] = rA * 32 + ((2 * ks + h + (rA >> 1)) & 3) * 8;
            const int rB = wx * 64 + ti * 32 + l31;
            offB[ks][ti] = rB * 32 + ((2 * ks + h + (rB >> 1)) & 3) * 8;
        }

    for (int k0 = 0; k0 < K; k0 += 32) {
        __syncthreads();
#pragma unroll
        for (int p = 0; p < 2; ++p) {
            const int cb = p * 256 + cwb;
            const ushort_t* ga = A  + (size_t)(brow + rS[p]) * K + k0 + gS[p] * 8;
            const ushort_t* gb = BT + (size_t)(bcol + rS[p]) * K + k0 + gS[p] * 8;
            __builtin_amdgcn_global_load_lds(
                (const __attribute__((address_space(1))) void*)ga,
                (__attribute__((address_space(3))) void*)(sA + (size_t)cb * 8), 16, 0, 0);
            __builtin_amdgcn_global_load_lds(
                (const __attribute__((address_space(1))) void*)gb,
                (__attribute__((address_space(3))) void*)(sB + (size_t)cb * 8), 16, 0, 0);
        }
        __syncthreads();

#pragma unroll
        for (int ks = 0; ks < 2; ++ks) {
            const bf16x8 a0 = *(const bf16x8*)(sA + offA[ks][0]);
            const bf16x8 a1 = *(const bf16x8*)(sA + offA[ks][1]);
            const bf16x8 b0 = *(const bf16x8*)(sB + offB[ks][0]);
            const bf16x8 b1 = *(const bf16x8*)(sB + offB[ks][1]);
            acc[0][0] = __builtin_amdgcn_mfma_f32_32x32x16_bf16(a0, b0, acc[0][0], 0, 0, 0);
            acc[0][1] = __builtin_amdgcn_mfma_f32_32x32x16_bf16(a0, b1, acc[0][1], 0, 0, 0);
            acc[1][0] = __builtin_amdgcn_mfma_f32_32x32x16_bf16(a1, b0, acc[1][0], 0, 0, 0);
            acc[1][1] = __builtin_amdgcn_mfma_f32_32x32x16_bf16(a1, b1, acc[1][1], 0, 0, 0);
        }
    }

    // epilogue: 32x32 C/D mapping col=lane&31, row=(reg&3)+8*(reg>>2)+4*(lane>>5)
    // [m74/m101 verified]
#pragma unroll
    for (int tj = 0; tj < 2; ++tj) {
        const int col = bcol + wx * 64 + tj * 32 + l31;
        const int bidx = PERM_BIAS ? ((col & 511) * 17 + (col >> 9)) : col;
        const float bv = bias[bidx];
#pragma unroll
        for (int ti = 0; ti < 2; ++ti) {
            const int rb = brow + wy * 64 + ti * 32 + 4 * h;
#pragma unroll
            for (int reg = 0; reg < 16; ++reg) {
                const int row = rb + (reg & 3) + 8 * (reg >> 2);
                C[(size_t)row * N_ + col] = f2bf(fast_tanh(acc[ti][tj][reg] + bv));
            }
        }
    }
}

// ---------------------------------------------------------------------------
// Spline postprocess, plane-major net layout: net[b][p*512 + n] holds value
// p of unit n (p<9: h_net, p>=9: w_net). One block per batch row, 256
// threads; thread t handles units 2t, 2t+1 via dword plane loads (coalesced).
// ---------------------------------------------------------------------------
__global__ __launch_bounds__(256) void spline_post(
    const ushort_t* __restrict__ net,   // rows x OUTD bf16, plane-major
    const float* __restrict__ v_in,     // rows x 2N
    const float* __restrict__ ld_in,    // rows
    float* __restrict__ v_out,          // rows x 2N
    float* __restrict__ ld_out)         // rows
{
    const int b = blockIdx.x;
    const int t = threadIdx.x;          // 0..255

    // 17 coalesced dword loads: planes p, units {2t, 2t+1}
    unsigned int pl[17];
    const ushort_t* base = net + (size_t)b * OUTD + 2 * t;
#pragma unroll
    for (int p = 0; p < 17; ++p)
        pl[p] = *(const unsigned int*)(base + p * 512);

    // passive copy (units 2t, 2t+1)
    {
        const float2 vp = *(const float2*)(v_in + (size_t)b * (2 * NN) + 2 * t);
        *(float2*)(v_out + (size_t)b * (2 * NN) + 2 * t) = vp;
    }
    const float2 va2 = *(const float2*)(v_in + (size_t)b * (2 * NN) + NN + 2 * t);

    float vact[2];
    float lt_sum = 0.f;
#pragma unroll 1
    for (int u = 0; u < 2; ++u) {
        const int sh = u * 16;
        float t17[17];
#pragma unroll
        for (int p = 0; p < 17; ++p)
            t17[p] = bf2f((ushort_t)(pl[p] >> sh));

        // softmax over w_net = t17[9..16]
        float m = t17[9];
#pragma unroll
        for (int i = 10; i < 17; i++) m = fmaxf(m, t17[i]);
        float wn[8], wsum = 0.f;
#pragma unroll
        for (int i = 0; i < 8; i++) { wn[i] = __expf(t17[9 + i] - m); wsum += wn[i]; }
        const float winv = 1.f / wsum;
#pragma unroll
        for (int i = 0; i < 8; i++) wn[i] *= winv;

        float eh[9];
#pragma unroll
        for (int i = 0; i < 9; i++) eh[i] = __expf(t17[i]);
        float denom = 0.f;
#pragma unroll
        for (int k = 0; k < 8; k++) denom += 0.5f * wn[k] * (eh[k] + eh[k + 1]);
        const float dinv = 1.f / denom;
        float hn[9];
#pragma unroll
        for (int i = 0; i < 9; i++) hn[i] = eh[i] * dinv;

        float kx[9], ky[9];
        kx[0] = 0.f; ky[0] = 0.f;
#pragma unroll
        for (int k = 0; k < 8; k++) {
            kx[k + 1] = kx[k] + wn[k];
            ky[k + 1] = ky[k] + 0.5f * wn[k] * (hn[k] + hn[k + 1]);
        }

        const float va = (u == 0) ? va2.x : va2.y;
        int cnt = 0;
#pragma unroll
        for (int j = 0; j < 9; j++) cnt += (kx[j] < va) ? 1 : 0;
        int k = cnt - 1;
        k = k < 0 ? 0 : (k > KKN - 1 ? KKN - 1 : k);

        const float wseg = wn[k];
        const float hlo = hn[k], hhi = hn[k + 1];
        const float xlo = kx[k], ylo = ky[k];
        const float alpha = (va - xlo) / wseg;
        vact[u] = ylo + alpha * hlo * wseg + 0.5f * alpha * alpha * (hhi - hlo) * wseg;
        lt_sum += __logf(hlo + alpha * (hhi - hlo));
    }

    *(float2*)(v_out + (size_t)b * (2 * NN) + NN + 2 * t) = make_float2(vact[0], vact[1]);

    // reduce lt_sum across 256 threads (4 waves)
    __shared__ float wred[4];
#pragma unroll
    for (int o = 32; o > 0; o >>= 1) lt_sum += __shfl_down(lt_sum, o, 64);
    if ((t & 63) == 0) wred[t >> 6] = lt_sum;
    __syncthreads();
    if (t == 0)
        ld_out[b] = ld_in[b] - (wred[0] + wred[1] + wred[2] + wred[3]);
}

// ---------------------------------------------------------------------------
extern "C" void kernel_launch(void* const* d_in, const int* in_sizes, int n_in,
                              void* d_out, int out_size, void* d_ws, size_t ws_size,
                              hipStream_t stream)
{
    const float* v_in = (const float*)d_in[0];   // B x 2N
    const float* ld   = (const float*)d_in[1];   // B x 1
    const float* W1   = (const float*)d_in[2];   // N x H
    const float* b1   = (const float*)d_in[3];   // H
    const float* W2   = (const float*)d_in[4];   // H x H
    const float* b2   = (const float*)d_in[5];   // H
    const float* W3   = (const float*)d_in[6];   // H x OUTD
    const float* b3   = (const float*)d_in[7];   // OUTD

    float* out    = (float*)d_out;
    float* v_out  = out;                           // B*2N
    float* ld_out = out + (size_t)BB * (2 * NN);   // B

    // Workspace tiers (R3-verified: full tier 172Mi fits):
    //   [0, region)       chunk net buffer (plane-major); a0b + x1b alias here
    //   [region, +16Mi)   x2b ; then W1T (1Mi) W2T (2Mi) W3T (17Mi)
    const size_t Mi = 1048576;
    int    chunk;
    size_t region;
    if      (ws_size >= 172 * Mi) { chunk = 8192; region = 136 * Mi; }
    else if (ws_size >= 104 * Mi) { chunk = 4096; region =  68 * Mi; }
    else if (ws_size >=  70 * Mi) { chunk = 2048; region =  34 * Mi; }
    else                          { chunk = 1024; region =  24 * Mi; }

    char* ws = (char*)d_ws;
    ushort_t* a0b = (ushort_t*)(ws);
    ushort_t* x1b = (ushort_t*)(ws + 8 * Mi);
    ushort_t* netc = (ushort_t*)(ws);                       // chunk buffer
    ushort_t* x2b = (ushort_t*)(ws + region);
    ushort_t* W1T = (ushort_t*)(ws + region + 16 * Mi);
    ushort_t* W2T = (ushort_t*)(ws + region + 17 * Mi);
    ushort_t* W3T = (ushort_t*)(ws + region + 19 * Mi);

    // conversions
    conv_v<<<dim3(BB * NN / 2 / 256), dim3(256), 0, stream>>>(v_in, a0b);
    transpose_cvt<false><<<dim3(HH / 32, NN / 32),   dim3(32, 8), 0, stream>>>(W1, W1T, NN, HH);
    transpose_cvt<false><<<dim3(HH / 32, HH / 32),   dim3(32, 8), 0, stream>>>(W2, W2T, HH, HH);
    transpose_cvt<true ><<<dim3(OUTD / 32, HH / 32), dim3(32, 8), 0, stream>>>(W3, W3T, HH, OUTD);

    // GEMM1: x1 = tanh((v_passive-0.5) @ W1 + b1)   M=8192 N=1024 K=512
    gemm_bt_tanh<false><<<dim3(HH / 128, BB / 128), dim3(256), 0, stream>>>(
        a0b, W1T, b1, x1b, HH, NN);
    // GEMM2: x2 = tanh(x1 @ W2 + b2)                M=8192 N=1024 K=1024
    gemm_bt_tanh<false><<<dim3(HH / 128, BB / 128), dim3(256), 0, stream>>>(
        x1b, W2T, b2, x2b, HH, HH);

    // GEMM3 + spline, chunked (single pass when chunk==8192)
    for (int c = 0; c < BB / chunk; ++c) {
        const ushort_t* xa = x2b + (size_t)c * chunk * HH;
        gemm_bt_tanh<true><<<dim3(OUTD / 128, chunk / 128), dim3(256), 0, stream>>>(
            xa, W3T, b3, netc, OUTD, HH);
        spline_post<<<dim3(chunk), dim3(256), 0, stream>>>(
            netc,
            v_in   + (size_t)c * chunk * (2 * NN),
            ld     + (size_t)c * chunk,
            v_out  + (size_t)c * chunk * (2 * NN),
            ld_out + (size_t)c * chunk);
    }
}